// Round 4
// baseline (2258.216 us; speedup 1.0000x reference)
//
#include <hip/hip_runtime.h>
#include <hip/hip_cooperative_groups.h>
#include <math.h>

namespace cg = cooperative_groups;

#define BN_SF 0.9999950000374997f  /* 1/sqrt(1+1e-5) */

typedef __attribute__((ext_vector_type(8))) short short8v;
typedef __attribute__((ext_vector_type(4))) float float4v;

__device__ __forceinline__ float sigm(float x) { return 1.0f / (1.0f + expf(-x)); }

__device__ __forceinline__ short f2bf(float x) {
    unsigned u = __builtin_bit_cast(unsigned, x);
    unsigned r = (u + 0x7fffu + ((u >> 16) & 1u)) >> 16;
    return (short)r;
}
__device__ __forceinline__ float bf2f(short h) {
    unsigned u = ((unsigned)(unsigned short)h) << 16;
    return __builtin_bit_cast(float, u);
}

struct Params {
    const float *lpr, *h0, *c0, *at0;
    const float *Wsp, *bsp, *bih, *bhh, *Whp, *bhp;
    const float *Wih, *Whh;
    const float *Wpat, *bpat, *Wm1, *bm1, *Wm2, *bm2, *Wd1, *bd1, *Wd2, *bd2;
    float *out;
    float *hA, *cbuf, *di, *ph, *uv;
    short *m1s, *Wm2s, *dh1f, *WgHi, *WgLo, *Wm1f, *Wd1f, *Wd2f;
};

// f32 [K][N] row-major -> bf16 B-fragment layout for mfma_f32_16x16x32_bf16
template <int K, int N>
__device__ __forceinline__ void cvtB(const float* __restrict__ src, short* __restrict__ dst,
                                     float scale, int i) {
    int k = i / N, n = i % N;
    size_t d = (size_t)(n >> 4) * (K >> 5) * 512 + (size_t)(k >> 5) * 512
             + (size_t)(((n & 15) + (((k & 31) >> 3) << 4)) << 3) + (k & 7);
    dst[d] = f2bf(scale * src[i]);
}

__global__ __launch_bounds__(512) void k_all(Params p) {
    cg::grid_group grid = cg::this_grid();
    int t = threadIdx.x, b = blockIdx.x;
    int l = t & 63, w = t >> 6;
    int gtid = b * 512 + t;  // 0..32767

    __shared__ float sh[16][128];
    __shared__ float sg[16][512];
    __shared__ float sdi[16][64];
    __shared__ short xfh[3072];
    __shared__ short xfl[3072];
    __shared__ short xm[2048];
    __shared__ float sat[16];
    __shared__ float srel[16][2];
    __shared__ short sphb[1024];
    __shared__ short shf[2][2048];
    __shared__ float rw[64];

    // ================= setup (weight conversion + init) =================
    for (int i = gtid; i < 512 * 1024; i += 32768)  cvtB<512, 1024>(p.Wm2, p.Wm2s, 1.f, i);
    for (int i = gtid; i < 1152 * 1024; i += 32768) cvtB<1152, 1024>(p.Wd1, p.Wd1f, 1.f, i);
    for (int i = gtid; i < 1024 * 128; i += 32768)  cvtB<1024, 128>(p.Wd2, p.Wd2f, 1.f, i);
    for (int i = gtid; i < 128 * 512; i += 32768)   cvtB<128, 512>(p.Wm1, p.Wm1f, 0.05f, i);
    for (int i = gtid; i < 192 * 512; i += 32768) {  // [W_ih;W_hh] hi/lo split
        int k = i >> 9, n = i & 511;
        float v = (k < 64) ? p.Wih[k * 512 + n] : p.Whh[(k - 64) * 512 + n];
        short hi = f2bf(v), lo = f2bf(v - bf2f(hi));
        size_t d = (size_t)(n >> 4) * 3072 + (size_t)(k >> 5) * 512
                 + (size_t)(((n & 15) + (((k & 31) >> 3) << 4)) << 3) + (k & 7);
        p.WgHi[d] = hi; p.WgLo[d] = lo;
    }
    for (int i = gtid; i < 1024 * 64; i += 32768) {  // di0
        int r = i >> 6, c = i & 63;
        p.di[i] = p.lpr[r * 2] * p.Wsp[c] + p.lpr[r * 2 + 1] * p.Wsp[64 + c] + p.bsp[c];
    }
    for (int i = gtid; i < 1024 * 128; i += 32768) p.cbuf[i] = p.c0[i];
    if (b == 0) {  // uv (rank-1 agent-type folding)
        if (t < 64) { float s = 0.f; for (int k = 0; k < 6; ++k) s += p.Wpat[k * 64 + t]; rw[t] = s; }
        __syncthreads();
        float u = 0.f, v = 0.f;
        for (int e = 0; e < 64; ++e) { float wg = p.Wm1[(128 + e) * 512 + t]; u += rw[e] * wg; v += p.bpat[e] * wg; }
        p.uv[t] = 0.05f * u; p.uv[512 + t] = 0.05f * v + p.bm1[t];
    }
    grid.sync();

    // ================= 12 decoder steps =================
    for (int st = 0; st < 12; ++st) {
        int first = (st == 0);
        float* outrel = p.out + (size_t)st * 2048;

        // ---- phase 1: dh2(prev) + LSTM(hi/lo) + rel + di_next + m1 ----
        {
            int r0 = b * 16;
            float4v hacc = {0.f, 0.f, 0.f, 0.f};
            if (!first) {
                const short* ap = p.dh1f + (size_t)b * 16384 + l * 8;
                const short* bp = p.Wd2f + (size_t)w * 16384 + l * 8;
                for (int kc = 0; kc < 32; ++kc) {
                    short8v a  = *(const short8v*)(ap + kc * 512);
                    short8v bb = *(const short8v*)(bp + kc * 512);
                    hacc = __builtin_amdgcn_mfma_f32_16x16x32_bf16(a, bb, hacc, 0, 0, 0);
                }
            }
            for (int i = t; i < 16 * 64; i += 512) sdi[i >> 6][i & 63] = p.di[r0 * 64 + i];
            if (t < 16) sat[t] = p.at0[r0 + t];
            if (first) {
                for (int i = t; i < 16 * 128; i += 512) sh[i >> 7][i & 127] = p.h0[r0 * 128 + i];
            } else {
                int col = w * 16 + (l & 15);
                float bb2 = p.bd2[col];
#pragma unroll
                for (int r = 0; r < 4; ++r) {
                    int row = ((l >> 4) << 2) + r;
                    sh[row][col] = fmaxf(BN_SF * (hacc[r] + bb2), 0.f);
                }
            }
            __syncthreads();

            // X=[di|h] hi/lo A-fragments
            for (int i = t; i < 6 * 512; i += 512) {
                int pos = i & 511, kc = i >> 9;
                int ll = pos >> 3, j = pos & 7;
                int row = ll & 15, k = kc * 32 + ((ll >> 4) << 3) + j;
                float v = (k < 64) ? sdi[row][k] : sh[row][k - 64];
                short hi = f2bf(v);
                xfh[i] = hi;
                xfl[i] = f2bf(v - bf2f(hi));
            }
            __syncthreads();

            // gates MFMA (3 hi/lo terms)
            {
                float4v ga[4] = {{0,0,0,0},{0,0,0,0},{0,0,0,0},{0,0,0,0}};
                for (int kc = 0; kc < 6; ++kc) {
                    short8v ah = *(const short8v*)(&xfh[kc * 512 + l * 8]);
                    short8v al = *(const short8v*)(&xfl[kc * 512 + l * 8]);
#pragma unroll
                    for (int q = 0; q < 4; ++q) {
                        int nf = w * 4 + q;
                        short8v bh = *(const short8v*)(p.WgHi + (size_t)nf * 3072 + kc * 512 + l * 8);
                        short8v bl = *(const short8v*)(p.WgLo + (size_t)nf * 3072 + kc * 512 + l * 8);
                        ga[q] = __builtin_amdgcn_mfma_f32_16x16x32_bf16(ah, bh, ga[q], 0, 0, 0);
                        ga[q] = __builtin_amdgcn_mfma_f32_16x16x32_bf16(ah, bl, ga[q], 0, 0, 0);
                        ga[q] = __builtin_amdgcn_mfma_f32_16x16x32_bf16(al, bh, ga[q], 0, 0, 0);
                    }
                }
#pragma unroll
                for (int q = 0; q < 4; ++q) {
                    int col = (w * 4 + q) * 16 + (l & 15);
                    float bb = p.bih[col] + p.bhh[col];
#pragma unroll
                    for (int r = 0; r < 4; ++r) {
                        int row = ((l >> 4) << 2) + r;
                        sg[row][col] = ga[q][r] + bb;
                    }
                }
            }
            __syncthreads();

            // LSTM pointwise (overwrites sh with new h)
            for (int i = t; i < 16 * 128; i += 512) {
                int row = i >> 7, j = i & 127;
                float gi = sg[row][j], gf = sg[row][j + 128], gg = sg[row][j + 256], go = sg[row][j + 384];
                float cn = sigm(gf) * p.cbuf[(r0 + row) * 128 + j] + sigm(gi) * tanhf(gg);
                float hn = sigm(go) * tanhf(cn);
                p.cbuf[(r0 + row) * 128 + j] = cn;
                sh[row][j] = hn;
                p.hA[(r0 + row) * 128 + j] = hn;
            }
            __syncthreads();

            // rel (f32 exact -> output)
            if (t < 32) {
                int row = t >> 1, d = t & 1;
                float s2 = p.bhp[d];
                for (int k = 0; k < 128; ++k) s2 += sh[row][k] * p.Whp[k * 2 + d];
                srel[row][d] = s2;
                outrel[(r0 + row) * 2 + d] = s2;
            }
            // new-h bf16 A-fragments
            for (int i = t; i < 4 * 512; i += 512) {
                int pos = i & 511, kc = i >> 9;
                int ll = pos >> 3, j = pos & 7;
                int row = ll & 15, k = kc * 32 + ((ll >> 4) << 3) + j;
                xm[i] = f2bf(sh[row][k]);
            }
            __syncthreads();

            // di_next
            for (int i = t; i < 16 * 64; i += 512) {
                int row = i >> 6, c = i & 63;
                p.di[(r0 + row) * 64 + c] = srel[row][0] * p.Wsp[c] + srel[row][1] * p.Wsp[64 + c] + p.bsp[c];
            }

            // m1 MFMA -> bf16 A-fragments for m2
            {
                float4v ma[4] = {{0,0,0,0},{0,0,0,0},{0,0,0,0},{0,0,0,0}};
                for (int kc = 0; kc < 4; ++kc) {
                    short8v a = *(const short8v*)(&xm[kc * 512 + l * 8]);
#pragma unroll
                    for (int q = 0; q < 4; ++q) {
                        int nf = w * 4 + q;
                        short8v bb = *(const short8v*)(p.Wm1f + (size_t)nf * 2048 + kc * 512 + l * 8);
                        ma[q] = __builtin_amdgcn_mfma_f32_16x16x32_bf16(a, bb, ma[q], 0, 0, 0);
                    }
                }
                int sS = b >> 1, mtS = b & 1;
#pragma unroll
                for (int q = 0; q < 4; ++q) {
                    int col = (w * 4 + q) * 16 + (l & 15);
                    float uc = p.uv[col], vc = p.uv[512 + col];
#pragma unroll
                    for (int r = 0; r < 4; ++r) {
                        int rowC = ((l >> 4) << 2) + r;
                        float pre = ma[q][r] + sat[rowC] * uc + vc;
                        float m1v = fmaxf(BN_SF * pre, 0.f);
                        int kcD = col >> 5;
                        int laneD = rowC + (((col & 31) >> 3) << 4);
                        p.m1s[(size_t)sS * 16384 + kcD * 1024 + mtS * 512 + laneD * 8 + (col & 7)] = f2bf(m1v);
                    }
                }
            }
        }
        grid.sync();

        // ---- phase 2: m2 = m1 @ Wm2 (MFMA), per-scene colmax, bnrelu -> ph ----
        {
            int s = b >> 1, half = b & 1;
            const short* ap = p.m1s + (size_t)s * 16384 + l * 8;
            const short* bp = p.Wm2s + (size_t)(half * 32 + w * 4) * 8192 + l * 8;
            float4v acc[2][4] = {};
            for (int kc = 0; kc < 16; ++kc) {
                short8v a0 = *(const short8v*)(ap + kc * 1024);
                short8v a1 = *(const short8v*)(ap + kc * 1024 + 512);
#pragma unroll
                for (int nt = 0; nt < 4; ++nt) {
                    short8v bb = *(const short8v*)(bp + nt * 8192 + kc * 512);
                    acc[0][nt] = __builtin_amdgcn_mfma_f32_16x16x32_bf16(a0, bb, acc[0][nt], 0, 0, 0);
                    acc[1][nt] = __builtin_amdgcn_mfma_f32_16x16x32_bf16(a1, bb, acc[1][nt], 0, 0, 0);
                }
            }
#pragma unroll
            for (int nt = 0; nt < 4; ++nt) {
                float m = acc[0][nt][0];
#pragma unroll
                for (int ri = 1; ri < 4; ++ri) m = fmaxf(m, acc[0][nt][ri]);
#pragma unroll
                for (int ri = 0; ri < 4; ++ri) m = fmaxf(m, acc[1][nt][ri]);
                m = fmaxf(m, __shfl_xor(m, 16, 64));
                m = fmaxf(m, __shfl_xor(m, 32, 64));
                if (l < 16) {
                    int col = (half * 32 + w * 4 + nt) * 16 + l;
                    p.ph[s * 1024 + col] = fmaxf(BN_SF * (m + p.bm2[col]), 0.f);
                }
            }
        }
        grid.sync();

        // ---- phase 3: phw (broadcast-A MFMA) + dh1h MFMA -> dh1f ----
        {
            int s = b >> 1, half = b & 1;
            for (int i = t; i < 1024; i += 512) sphb[i] = f2bf(p.ph[s * 1024 + i]);
            for (int i = t; i < 4096; i += 512) {
                int mt = i >> 11, pos = i & 2047;
                int kc = pos >> 9, ll = (pos >> 3) & 63, j = pos & 7;
                int row = ll & 15, k = kc * 32 + ((ll >> 4) << 3) + j;
                shf[mt][pos] = f2bf(p.hA[(s * 32 + mt * 16 + row) * 128 + k]);
            }
            __syncthreads();
            float4v accp[4], acch[4][2];
#pragma unroll
            for (int q = 0; q < 4; ++q) {
                int col = (half * 32 + w * 4 + q) * 16 + (l & 15);
                float bb = p.bd1[col];
                accp[q] = (float4v){bb, bb, bb, bb};
                acch[q][0] = (float4v){0.f, 0.f, 0.f, 0.f};
                acch[q][1] = (float4v){0.f, 0.f, 0.f, 0.f};
            }
            for (int kc = 0; kc < 32; ++kc) {
                short8v a = *(const short8v*)(&sphb[kc * 32 + ((l >> 4) << 3)]);
#pragma unroll
                for (int q = 0; q < 4; ++q) {
                    int nt = half * 32 + w * 4 + q;
                    short8v bb = *(const short8v*)(p.Wd1f + (size_t)nt * 18432 + (size_t)(4 + kc) * 512 + l * 8);
                    accp[q] = __builtin_amdgcn_mfma_f32_16x16x32_bf16(a, bb, accp[q], 0, 0, 0);
                }
            }
            for (int kc = 0; kc < 4; ++kc) {
                short8v a0 = *(const short8v*)(&shf[0][kc * 512 + l * 8]);
                short8v a1 = *(const short8v*)(&shf[1][kc * 512 + l * 8]);
#pragma unroll
                for (int q = 0; q < 4; ++q) {
                    int nt = half * 32 + w * 4 + q;
                    short8v bb = *(const short8v*)(p.Wd1f + (size_t)nt * 18432 + (size_t)kc * 512 + l * 8);
                    acch[q][0] = __builtin_amdgcn_mfma_f32_16x16x32_bf16(a0, bb, acch[q][0], 0, 0, 0);
                    acch[q][1] = __builtin_amdgcn_mfma_f32_16x16x32_bf16(a1, bb, acch[q][1], 0, 0, 0);
                }
            }
#pragma unroll
            for (int q = 0; q < 4; ++q) {
                int col = (half * 32 + w * 4 + q) * 16 + (l & 15);
                int kcD = col >> 5, j = col & 7;
                int lhi = ((col & 31) >> 3) << 4;
#pragma unroll
                for (int mt = 0; mt < 2; ++mt) {
#pragma unroll
                    for (int r = 0; r < 4; ++r) {
                        int rowC = ((l >> 4) << 2) + r;
                        float v = fmaxf(BN_SF * (acch[q][mt][r] + accp[q][r]), 0.f);
                        p.dh1f[(size_t)(s * 2 + mt) * 16384 + (size_t)kcD * 512 + (rowC + lhi) * 8 + j] = f2bf(v);
                    }
                }
            }
        }
        grid.sync();
    }

    // ================= final: h = relu(BN*(dh1 @ Wd2 + bd2)) -> out =================
    {
        float* outh = p.out + 24576;
        float4v acc = {0.f, 0.f, 0.f, 0.f};
        const short* ap = p.dh1f + (size_t)b * 16384 + l * 8;
        const short* bp = p.Wd2f + (size_t)w * 16384 + l * 8;
        for (int kc = 0; kc < 32; ++kc) {
            short8v a  = *(const short8v*)(ap + kc * 512);
            short8v bb = *(const short8v*)(bp + kc * 512);
            acc = __builtin_amdgcn_mfma_f32_16x16x32_bf16(a, bb, acc, 0, 0, 0);
        }
        int col = w * 16 + (l & 15);
        float bb2 = p.bd2[col];
#pragma unroll
        for (int r = 0; r < 4; ++r) {
            int row = ((l >> 4) << 2) + r;
            outh[(b * 16 + row) * 128 + col] = fmaxf(BN_SF * (acc[r] + bb2), 0.f);
        }
    }
}

extern "C" void kernel_launch(void* const* d_in, const int* in_sizes, int n_in,
                              void* d_out, int out_size, void* d_ws, size_t ws_size,
                              hipStream_t stream) {
    Params pa;
    pa.lpr  = (const float*)d_in[1];
    pa.h0   = (const float*)d_in[2];
    pa.c0   = (const float*)d_in[3];
    pa.at0  = (const float*)d_in[6];
    pa.Wsp  = (const float*)d_in[8];
    pa.bsp  = (const float*)d_in[9];
    pa.Wih  = (const float*)d_in[10];
    pa.Whh  = (const float*)d_in[11];
    pa.bih  = (const float*)d_in[12];
    pa.bhh  = (const float*)d_in[13];
    pa.Whp  = (const float*)d_in[14];
    pa.bhp  = (const float*)d_in[15];
    pa.Wpat = (const float*)d_in[20];
    pa.bpat = (const float*)d_in[21];
    pa.Wm1  = (const float*)d_in[26];
    pa.bm1  = (const float*)d_in[27];
    pa.Wm2  = (const float*)d_in[28];
    pa.bm2  = (const float*)d_in[29];
    pa.Wd1  = (const float*)d_in[30];
    pa.bd1  = (const float*)d_in[31];
    pa.Wd2  = (const float*)d_in[32];
    pa.bd2  = (const float*)d_in[33];
    pa.out  = (float*)d_out;

    float* ws = (float*)d_ws;
    pa.hA   = ws;                    // 131072 f
    pa.cbuf = pa.hA + 131072;        // 131072 f
    pa.di   = pa.cbuf + 131072;      // 65536 f
    pa.ph   = pa.di + 65536;         // 32768 f
    pa.uv   = pa.ph + 32768;         // 1024 f
    pa.m1s  = (short*)(pa.uv + 1024);   // 524288 sh
    pa.Wm2s = pa.m1s + 524288;          // 524288 sh
    pa.dh1f = pa.Wm2s + 524288;         // 1048576 sh
    pa.WgHi = pa.dh1f + 1048576;        // 98304 sh
    pa.WgLo = pa.WgHi + 98304;          // 98304 sh
    pa.Wm1f = pa.WgLo + 98304;          // 65536 sh
    pa.Wd1f = pa.Wm1f + 65536;          // 1179648 sh
    pa.Wd2f = pa.Wd1f + 1179648;        // 131072 sh

    void* kargs[] = { (void*)&pa };
    hipLaunchCooperativeKernel((const void*)k_all, dim3(64), dim3(512), kargs, 0, stream);
}

// Round 5
// 2077.412 us; speedup vs baseline: 1.0870x; 1.0870x over previous
//
#include <hip/hip_runtime.h>
#include <math.h>

#define BN_SF 0.9999950000374997f  /* 1/sqrt(1+1e-5) */

typedef __attribute__((ext_vector_type(8))) short short8v;
typedef __attribute__((ext_vector_type(4))) float float4v;

__device__ __forceinline__ float sigm(float x) { return 1.0f / (1.0f + expf(-x)); }

__device__ __forceinline__ short f2bf(float x) {
    unsigned u = __builtin_bit_cast(unsigned, x);
    unsigned r = (u + 0x7fffu + ((u >> 16) & 1u)) >> 16;
    return (short)r;
}
__device__ __forceinline__ float bf2f(short h) {
    unsigned u = ((unsigned)(unsigned short)h) << 16;
    return __builtin_bit_cast(float, u);
}

// f32 [K][N] row-major -> bf16 B-fragment layout for mfma_f32_16x16x32_bf16
template <int K, int N>
__device__ __forceinline__ void cvtB(const float* __restrict__ src, short* __restrict__ dst,
                                     float scale, int i) {
    int k = i / N, n = i % N;
    size_t d = (size_t)(n >> 4) * (K >> 5) * 512 + (size_t)(k >> 5) * 512
             + (size_t)(((n & 15) + (((k & 31) >> 3) << 4)) << 3) + (k & 7);
    dst[d] = f2bf(scale * src[i]);
}

struct SetupP {
    const float *Wm2, *Wd1, *Wd2, *Wm1, *Wih, *Whh, *Wpat, *bpat, *bm1;
    short *Wm2s, *Wd1f, *Wd2f, *Wm1f, *WgHi, *WgLo;
    float *uv;
};

__global__ __launch_bounds__(256) void k_setup(SetupP p) {
    int gt = blockIdx.x * 256 + threadIdx.x;
    int stride = gridDim.x * 256;
    for (int i = gt; i < 512 * 1024; i += stride)  cvtB<512, 1024>(p.Wm2, p.Wm2s, 1.f, i);
    for (int i = gt; i < 1152 * 1024; i += stride) cvtB<1152, 1024>(p.Wd1, p.Wd1f, 1.f, i);
    for (int i = gt; i < 1024 * 128; i += stride)  cvtB<1024, 128>(p.Wd2, p.Wd2f, 1.f, i);
    for (int i = gt; i < 128 * 512; i += stride)   cvtB<128, 512>(p.Wm1, p.Wm1f, 0.05f, i);
    for (int i = gt; i < 192 * 512; i += stride) {  // [W_ih;W_hh] hi/lo split
        int k = i >> 9, n = i & 511;
        float v = (k < 64) ? p.Wih[k * 512 + n] : p.Whh[(k - 64) * 512 + n];
        short hi = f2bf(v), lo = f2bf(v - bf2f(hi));
        size_t d = (size_t)(n >> 4) * 3072 + (size_t)(k >> 5) * 512
                 + (size_t)(((n & 15) + (((k & 31) >> 3) << 4)) << 3) + (k & 7);
        p.WgHi[d] = hi; p.WgLo[d] = lo;
    }
    if (blockIdx.x == 0) {  // uv: rank-1 agent-type folding (0.05 folded into u,v)
        __shared__ float rw[64];
        int t = threadIdx.x;
        if (t < 64) { float s = 0.f; for (int k = 0; k < 6; ++k) s += p.Wpat[k * 64 + t]; rw[t] = s; }
        __syncthreads();
        for (int c = t; c < 512; c += 256) {
            float u = 0.f, v = 0.f;
            for (int e = 0; e < 64; ++e) {
                float wg = p.Wm1[(128 + e) * 512 + c];
                u += rw[e] * wg; v += p.bpat[e] * wg;
            }
            p.uv[c] = 0.05f * u; p.uv[512 + c] = 0.05f * v + p.bm1[c];
        }
    }
}

struct MainP {
    const float *lpr, *h0, *c0, *at0;
    const float *Wsp, *bsp, *bih, *bhh, *Whp, *bhp;
    const float *bm2, *bd1, *bd2, *uv;
    const short *Wm2s, *Wd1f, *Wd2f, *Wm1f, *WgHi, *WgLo;
    float *out;
};

// 32 blocks (1 scene each) x 1024 threads (16 waves). All 12 steps in-block.
// LDS union "uni": X hi/lo A-frags (read P1) time-share with m1 A-frags (write P2, read P3).
__global__ __launch_bounds__(1024) void k_main(MainP p) {
    __shared__ short uni[16384];     // 32 KB: XFH/XFL | M1F
    __shared__ short dh1f[32768];    // 64 KB: dh1 A-frags [mt2][kc32][512]
    __shared__ float shF[32][132];   // h_new f32 (padded)
    __shared__ short xmf[4096];      // h_new A-frags [mt2][kc4][512]
    __shared__ short sphb[1024];     // ph bf16, linear k order
    __shared__ float srel[64];
    __shared__ float sat[32];

    const int t = threadIdx.x, s = blockIdx.x;
    const int l = t & 63, w = t >> 6;
    const int mt = w >> 3, w8 = w & 7;
    const int colb = w8 * 16 + (l & 15);
    const int rbase = (l >> 4) << 2;

#define XFH(m) (uni + (m) * 3072)
#define XFL(m) (uni + 6144 + (m) * 3072)
#define M1F(m) (uni + (m) * 8192)

    if (t < 32) sat[t] = p.at0[s * 32 + t];
    float cr[4];
#pragma unroll
    for (int r = 0; r < 4; ++r)
        cr[r] = p.c0[(s * 32 + mt * 16 + rbase + r) * 128 + colb];

    // di0 = lpr @ Wsp + bsp -> xf kc0..1 (hi/lo)
    for (int i = t; i < 2048; i += 1024) {
        int row = i >> 6, c = i & 63;
        float dv = p.lpr[(s * 32 + row) * 2] * p.Wsp[c]
                 + p.lpr[(s * 32 + row) * 2 + 1] * p.Wsp[64 + c] + p.bsp[c];
        short hi = f2bf(dv);
        int off = (c >> 5) * 512 + ((row & 15) + (((c & 31) >> 3) << 4)) * 8 + (c & 7);
        XFH(row >> 4)[off] = hi; XFL(row >> 4)[off] = f2bf(dv - bf2f(hi));
    }

    for (int st = 0; st < 12; ++st) {
        // ---- P0: h_in (h0 or dh2 of prev dh1) -> xf kc2..5 hi/lo ----
        if (st == 0) {
            for (int i = t; i < 4096; i += 1024) {
                int m2 = i >> 11, pos = i & 2047;
                int kc = pos >> 9, ll = (pos >> 3) & 63, j = pos & 7;
                int row = m2 * 16 + (ll & 15), kh = kc * 32 + ((ll >> 4) << 3) + j;
                float v = p.h0[(s * 32 + row) * 128 + kh];
                short hi = f2bf(v);
                XFH(m2)[(kc + 2) * 512 + ll * 8 + j] = hi;
                XFL(m2)[(kc + 2) * 512 + ll * 8 + j] = f2bf(v - bf2f(hi));
            }
        } else {
            float4v hacc = {0.f, 0.f, 0.f, 0.f};
            const short* ap = dh1f + mt * 16384 + l * 8;
            const short* bp = p.Wd2f + (size_t)w8 * 16384 + l * 8;
            for (int kc = 0; kc < 32; ++kc) {
                short8v a  = *(const short8v*)(ap + kc * 512);
                short8v bb = *(const short8v*)(bp + kc * 512);
                hacc = __builtin_amdgcn_mfma_f32_16x16x32_bf16(a, bb, hacc, 0, 0, 0);
            }
            int kx = 64 + colb, kcx = kx >> 5, jx = kx & 7, lxb = ((kx & 31) >> 3) << 4;
            float bb2 = p.bd2[colb];
#pragma unroll
            for (int r = 0; r < 4; ++r) {
                float hn = fmaxf(BN_SF * (hacc[r] + bb2), 0.f);
                short hi = f2bf(hn);
                int off = kcx * 512 + (rbase + r + lxb) * 8 + jx;
                XFH(mt)[off] = hi; XFL(mt)[off] = f2bf(hn - bf2f(hi));
            }
        }
        __syncthreads();  // S1

        // ---- P1: gates (3-term hi/lo MFMA) + LSTM pointwise (c in regs) ----
        {
            float4v ga[4] = {{0,0,0,0},{0,0,0,0},{0,0,0,0},{0,0,0,0}};
            for (int kc = 0; kc < 6; ++kc) {
                short8v ah = *(const short8v*)(XFH(mt) + kc * 512 + l * 8);
                short8v al = *(const short8v*)(XFL(mt) + kc * 512 + l * 8);
#pragma unroll
                for (int q = 0; q < 4; ++q) {
                    int nf = w8 + 8 * q;
                    short8v bh = *(const short8v*)(p.WgHi + (size_t)nf * 3072 + kc * 512 + l * 8);
                    short8v bl = *(const short8v*)(p.WgLo + (size_t)nf * 3072 + kc * 512 + l * 8);
                    ga[q] = __builtin_amdgcn_mfma_f32_16x16x32_bf16(ah, bh, ga[q], 0, 0, 0);
                    ga[q] = __builtin_amdgcn_mfma_f32_16x16x32_bf16(ah, bl, ga[q], 0, 0, 0);
                    ga[q] = __builtin_amdgcn_mfma_f32_16x16x32_bf16(al, bh, ga[q], 0, 0, 0);
                }
            }
            float bI = p.bih[colb]       + p.bhh[colb];
            float bF = p.bih[colb + 128] + p.bhh[colb + 128];
            float bG = p.bih[colb + 256] + p.bhh[colb + 256];
            float bO = p.bih[colb + 384] + p.bhh[colb + 384];
            int kcm = colb >> 5, jm = colb & 7, lmb = ((colb & 31) >> 3) << 4;
#pragma unroll
            for (int r = 0; r < 4; ++r) {
                int row = mt * 16 + rbase + r;
                float cn = sigm(ga[1][r] + bF) * cr[r] + sigm(ga[0][r] + bI) * tanhf(ga[2][r] + bG);
                cr[r] = cn;
                float hn = sigm(ga[3][r] + bO) * tanhf(cn);
                shF[row][colb] = hn;
                xmf[mt * 2048 + kcm * 512 + (rbase + r + lmb) * 8 + jm] = f2bf(hn);
            }
        }
        __syncthreads();  // S2

        // ---- P2: rel (f32, exact -> out) + m1 MFMA -> M1F (union) ----
        if (t < 512) {
            int row = t >> 4, d = (t >> 3) & 1, seg = t & 7;
            float v = 0.f;
#pragma unroll
            for (int kk = 0; kk < 16; ++kk) {
                int k = seg * 16 + kk;
                v += shF[row][k] * p.Whp[k * 2 + d];
            }
            v += __shfl_xor(v, 1, 64); v += __shfl_xor(v, 2, 64); v += __shfl_xor(v, 4, 64);
            if (seg == 0) {
                v += p.bhp[d];
                srel[row * 2 + d] = v;
                p.out[(size_t)st * 2048 + (s * 32 + row) * 2 + d] = v;
            }
        }
        {
            float4v ma[4] = {{0,0,0,0},{0,0,0,0},{0,0,0,0},{0,0,0,0}};
            for (int kc = 0; kc < 4; ++kc) {
                short8v a = *(const short8v*)(xmf + mt * 2048 + kc * 512 + l * 8);
#pragma unroll
                for (int q = 0; q < 4; ++q) {
                    int nf = w8 * 4 + q;
                    short8v bb = *(const short8v*)(p.Wm1f + (size_t)nf * 2048 + kc * 512 + l * 8);
                    ma[q] = __builtin_amdgcn_mfma_f32_16x16x32_bf16(a, bb, ma[q], 0, 0, 0);
                }
            }
#pragma unroll
            for (int q = 0; q < 4; ++q) {
                int col = (w8 * 4 + q) * 16 + (l & 15);
                float uc = p.uv[col], vc = p.uv[512 + col];
                int kcA = col >> 5, jA = col & 7, lA = ((col & 31) >> 3) << 4;
#pragma unroll
                for (int r = 0; r < 4; ++r) {
                    int rowC = mt * 16 + rbase + r;
                    float m1v = fmaxf(BN_SF * (ma[q][r] + sat[rowC] * uc + vc), 0.f);
                    M1F(mt)[kcA * 512 + (rbase + r + lA) * 8 + jA] = f2bf(m1v);
                }
            }
        }
        __syncthreads();  // S3

        // ---- P3: m2 MFMA + per-scene colmax -> sphb ----
        {
            float4v acc2[2][4] = {{{0,0,0,0},{0,0,0,0},{0,0,0,0},{0,0,0,0}},
                                  {{0,0,0,0},{0,0,0,0},{0,0,0,0},{0,0,0,0}}};
            const short* a0p = M1F(0) + l * 8;
            const short* a1p = M1F(1) + l * 8;
            const short* bp = p.Wm2s + (size_t)(w * 4) * 8192 + l * 8;
            for (int kc = 0; kc < 16; ++kc) {
                short8v a0 = *(const short8v*)(a0p + kc * 512);
                short8v a1 = *(const short8v*)(a1p + kc * 512);
#pragma unroll
                for (int q = 0; q < 4; ++q) {
                    short8v bb = *(const short8v*)(bp + q * 8192 + kc * 512);
                    acc2[0][q] = __builtin_amdgcn_mfma_f32_16x16x32_bf16(a0, bb, acc2[0][q], 0, 0, 0);
                    acc2[1][q] = __builtin_amdgcn_mfma_f32_16x16x32_bf16(a1, bb, acc2[1][q], 0, 0, 0);
                }
            }
#pragma unroll
            for (int q = 0; q < 4; ++q) {
                float m = acc2[0][q][0];
#pragma unroll
                for (int ri = 1; ri < 4; ++ri) m = fmaxf(m, acc2[0][q][ri]);
#pragma unroll
                for (int ri = 0; ri < 4; ++ri) m = fmaxf(m, acc2[1][q][ri]);
                m = fmaxf(m, __shfl_xor(m, 16, 64));
                m = fmaxf(m, __shfl_xor(m, 32, 64));
                if (l < 16) {
                    int col = (w * 4 + q) * 16 + l;
                    sphb[col] = f2bf(fmaxf(BN_SF * (m + p.bm2[col]), 0.f));
                }
            }
        }
        __syncthreads();  // S4

        // ---- P4: di_next -> xf kc0..1 ; phw (broadcast-A) + dh1h -> dh1f ----
        for (int i = t; i < 2048; i += 1024) {
            int row = i >> 6, c = i & 63;
            float dv = srel[row * 2] * p.Wsp[c] + srel[row * 2 + 1] * p.Wsp[64 + c] + p.bsp[c];
            short hi = f2bf(dv);
            int off = (c >> 5) * 512 + ((row & 15) + (((c & 31) >> 3) << 4)) * 8 + (c & 7);
            XFH(row >> 4)[off] = hi; XFL(row >> 4)[off] = f2bf(dv - bf2f(hi));
        }
        {
            float4v accp[4], acch[4][2];
#pragma unroll
            for (int q = 0; q < 4; ++q) {
                int col = (w * 4 + q) * 16 + (l & 15);
                float bb = p.bd1[col];
                accp[q] = (float4v){bb, bb, bb, bb};
                acch[q][0] = (float4v){0.f, 0.f, 0.f, 0.f};
                acch[q][1] = (float4v){0.f, 0.f, 0.f, 0.f};
            }
            for (int kc = 0; kc < 32; ++kc) {
                short8v a = *(const short8v*)(sphb + kc * 32 + ((l >> 4) << 3));
#pragma unroll
                for (int q = 0; q < 4; ++q) {
                    int nf = w * 4 + q;
                    short8v bb = *(const short8v*)(p.Wd1f + (size_t)nf * 18432 + (size_t)(4 + kc) * 512 + l * 8);
                    accp[q] = __builtin_amdgcn_mfma_f32_16x16x32_bf16(a, bb, accp[q], 0, 0, 0);
                }
            }
            for (int kc = 0; kc < 4; ++kc) {
                short8v a0 = *(const short8v*)(xmf + kc * 512 + l * 8);
                short8v a1 = *(const short8v*)(xmf + 2048 + kc * 512 + l * 8);
#pragma unroll
                for (int q = 0; q < 4; ++q) {
                    int nf = w * 4 + q;
                    short8v bb = *(const short8v*)(p.Wd1f + (size_t)nf * 18432 + (size_t)kc * 512 + l * 8);
                    acch[q][0] = __builtin_amdgcn_mfma_f32_16x16x32_bf16(a0, bb, acch[q][0], 0, 0, 0);
                    acch[q][1] = __builtin_amdgcn_mfma_f32_16x16x32_bf16(a1, bb, acch[q][1], 0, 0, 0);
                }
            }
#pragma unroll
            for (int q = 0; q < 4; ++q) {
                int col = (w * 4 + q) * 16 + (l & 15);
                int kcD = col >> 5, jD = col & 7, lD = ((col & 31) >> 3) << 4;
#pragma unroll
                for (int m2i = 0; m2i < 2; ++m2i) {
#pragma unroll
                    for (int r = 0; r < 4; ++r) {
                        float v = fmaxf(BN_SF * (acch[q][m2i][r] + accp[q][r]), 0.f);
                        dh1f[m2i * 16384 + kcD * 512 + (rbase + r + lD) * 8 + jD] = f2bf(v);
                    }
                }
            }
        }
        __syncthreads();  // S5
    }

    // ---- epilogue: final h = relu(BN*(dh1 @ Wd2 + bd2)) -> out ----
    {
        float4v hacc = {0.f, 0.f, 0.f, 0.f};
        const short* ap = dh1f + mt * 16384 + l * 8;
        const short* bp = p.Wd2f + (size_t)w8 * 16384 + l * 8;
        for (int kc = 0; kc < 32; ++kc) {
            short8v a  = *(const short8v*)(ap + kc * 512);
            short8v bb = *(const short8v*)(bp + kc * 512);
            hacc = __builtin_amdgcn_mfma_f32_16x16x32_bf16(a, bb, hacc, 0, 0, 0);
        }
        float bb2 = p.bd2[colb];
#pragma unroll
        for (int r = 0; r < 4; ++r)
            p.out[24576 + (s * 32 + mt * 16 + rbase + r) * 128 + colb] =
                fmaxf(BN_SF * (hacc[r] + bb2), 0.f);
    }
#undef XFH
#undef XFL
#undef M1F
}

extern "C" void kernel_launch(void* const* d_in, const int* in_sizes, int n_in,
                              void* d_out, int out_size, void* d_ws, size_t ws_size,
                              hipStream_t stream) {
    float* ws = (float*)d_ws;
    float* uv   = ws;                       // 1024 f32
    short* sbase = (short*)(ws + 1024);
    short* Wm2s = sbase;                    // 524288
    short* Wd1f = Wm2s + 524288;            // 1179648
    short* Wd2f = Wd1f + 1179648;           // 131072
    short* Wm1f = Wd2f + 131072;            // 65536
    short* WgHi = Wm1f + 65536;             // 98304
    short* WgLo = WgHi + 98304;             // 98304

    SetupP sp;
    sp.Wm2  = (const float*)d_in[28];
    sp.Wd1  = (const float*)d_in[30];
    sp.Wd2  = (const float*)d_in[32];
    sp.Wm1  = (const float*)d_in[26];
    sp.Wih  = (const float*)d_in[10];
    sp.Whh  = (const float*)d_in[11];
    sp.Wpat = (const float*)d_in[20];
    sp.bpat = (const float*)d_in[21];
    sp.bm1  = (const float*)d_in[27];
    sp.Wm2s = Wm2s; sp.Wd1f = Wd1f; sp.Wd2f = Wd2f;
    sp.Wm1f = Wm1f; sp.WgHi = WgHi; sp.WgLo = WgLo;
    sp.uv = uv;

    MainP mp;
    mp.lpr  = (const float*)d_in[1];
    mp.h0   = (const float*)d_in[2];
    mp.c0   = (const float*)d_in[3];
    mp.at0  = (const float*)d_in[6];
    mp.Wsp  = (const float*)d_in[8];
    mp.bsp  = (const float*)d_in[9];
    mp.bih  = (const float*)d_in[12];
    mp.bhh  = (const float*)d_in[13];
    mp.Whp  = (const float*)d_in[14];
    mp.bhp  = (const float*)d_in[15];
    mp.bm2  = (const float*)d_in[29];
    mp.bd1  = (const float*)d_in[31];
    mp.bd2  = (const float*)d_in[33];
    mp.uv   = uv;
    mp.Wm2s = Wm2s; mp.Wd1f = Wd1f; mp.Wd2f = Wd2f;
    mp.Wm1f = Wm1f; mp.WgHi = WgHi; mp.WgLo = WgLo;
    mp.out  = (float*)d_out;

    k_setup<<<2048, 256, 0, stream>>>(sp);
    k_main<<<32, 1024, 0, stream>>>(mp);
}

// Round 6
// 1066.067 us; speedup vs baseline: 2.1183x; 1.9487x over previous
//
#include <hip/hip_runtime.h>
#include <math.h>

#define BN_SF 0.9999950000374997f  /* 1/sqrt(1+1e-5) */

typedef __attribute__((ext_vector_type(8))) short short8v;
typedef __attribute__((ext_vector_type(4))) float float4v;

__device__ __forceinline__ float sigm(float x) { return 1.0f / (1.0f + expf(-x)); }

__device__ __forceinline__ short f2bf(float x) {
    unsigned u = __builtin_bit_cast(unsigned, x);
    unsigned r = (u + 0x7fffu + ((u >> 16) & 1u)) >> 16;
    return (short)r;
}
__device__ __forceinline__ float bf2f(short h) {
    unsigned u = ((unsigned)(unsigned short)h) << 16;
    return __builtin_bit_cast(float, u);
}

// f32 [K][N] row-major -> bf16 B-fragment layout for mfma_f32_16x16x32_bf16
template <int K, int N>
__device__ __forceinline__ void cvtB(const float* __restrict__ src, short* __restrict__ dst,
                                     float scale, int i) {
    int k = i / N, n = i % N;
    size_t d = (size_t)(n >> 4) * (K >> 5) * 512 + (size_t)(k >> 5) * 512
             + (size_t)(((n & 15) + (((k & 31) >> 3) << 4)) << 3) + (k & 7);
    dst[d] = f2bf(scale * src[i]);
}

struct SetupP {
    const float *Wm2, *Wd1, *Wd2, *Wm1, *Wih, *Whh, *Wpat, *bpat, *bm1;
    short *Wm2s, *Wd1f, *Wd2f, *Wm1f, *WgHi, *WgLo;
    float *uv;
};

__global__ __launch_bounds__(256) void k_setup(SetupP p) {
    int gt = blockIdx.x * 256 + threadIdx.x;
    int stride = gridDim.x * 256;
    for (int i = gt; i < 512 * 1024; i += stride)  cvtB<512, 1024>(p.Wm2, p.Wm2s, 1.f, i);
    for (int i = gt; i < 1152 * 1024; i += stride) cvtB<1152, 1024>(p.Wd1, p.Wd1f, 1.f, i);
    for (int i = gt; i < 1024 * 128; i += stride)  cvtB<1024, 128>(p.Wd2, p.Wd2f, 1.f, i);
    for (int i = gt; i < 128 * 512; i += stride)   cvtB<128, 512>(p.Wm1, p.Wm1f, 0.05f, i);
    for (int i = gt; i < 192 * 512; i += stride) {  // [W_ih;W_hh] hi/lo split
        int k = i >> 9, n = i & 511;
        float v = (k < 64) ? p.Wih[k * 512 + n] : p.Whh[(k - 64) * 512 + n];
        short hi = f2bf(v), lo = f2bf(v - bf2f(hi));
        size_t d = (size_t)(n >> 4) * 3072 + (size_t)(k >> 5) * 512
                 + (size_t)(((n & 15) + (((k & 31) >> 3) << 4)) << 3) + (k & 7);
        p.WgHi[d] = hi; p.WgLo[d] = lo;
    }
    if (blockIdx.x == 0) {  // uv: rank-1 agent-type folding (0.05 folded into u,v)
        __shared__ float rw[64];
        int t = threadIdx.x;
        if (t < 64) { float s = 0.f; for (int k = 0; k < 6; ++k) s += p.Wpat[k * 64 + t]; rw[t] = s; }
        __syncthreads();
        for (int c = t; c < 512; c += 256) {
            float u = 0.f, v = 0.f;
            for (int e = 0; e < 64; ++e) {
                float wg = p.Wm1[(128 + e) * 512 + c];
                u += rw[e] * wg; v += p.bpat[e] * wg;
            }
            p.uv[c] = 0.05f * u; p.uv[512 + c] = 0.05f * v + p.bm1[c];
        }
    }
}

struct MainP {
    const float *lpr, *h0, *c0, *at0;
    const float *Wsp, *bsp, *bih, *bhh, *Whp, *bhp;
    const float *bm2, *bd1, *bd2, *uv;
    const short *Wm2s, *Wd1f, *Wd2f, *Wm1f, *WgHi, *WgLo;
    float *out;
};

// 32 blocks (1 scene each) x 1024 threads (16 waves). All 12 steps in-block.
// All MFMA loops use batched independent loads (8-16 in flight) to hide L2/L3 latency.
__global__ __launch_bounds__(1024) void k_main(MainP p) {
    __shared__ short uni[16384];     // 32 KB: XFH/XFL | M1F (time-multiplexed)
    __shared__ short dh1f[32768];    // 64 KB: dh1 A-frags [mt2][kc32][512]
    __shared__ float shF[32][132];   // h_new f32 (padded)
    __shared__ short xmf[4096];      // h_new A-frags [mt2][kc4][512]
    __shared__ short sphb[1024];     // ph bf16, linear k order
    __shared__ float srel[64];
    __shared__ float sat[32];

    const int t = threadIdx.x, s = blockIdx.x;
    const int l = t & 63, w = t >> 6;
    const int mt = w >> 3, w8 = w & 7;
    const int colb = w8 * 16 + (l & 15);
    const int rbase = (l >> 4) << 2;

#define XFH(m) (uni + (m) * 3072)
#define XFL(m) (uni + 6144 + (m) * 3072)
#define M1F(m) (uni + (m) * 8192)

    if (t < 32) sat[t] = p.at0[s * 32 + t];
    float cr[4];
#pragma unroll
    for (int r = 0; r < 4; ++r)
        cr[r] = p.c0[(s * 32 + mt * 16 + rbase + r) * 128 + colb];

    // di0 = lpr @ Wsp + bsp -> xf kc0..1 (hi/lo)
    for (int i = t; i < 2048; i += 1024) {
        int row = i >> 6, c = i & 63;
        float dv = p.lpr[(s * 32 + row) * 2] * p.Wsp[c]
                 + p.lpr[(s * 32 + row) * 2 + 1] * p.Wsp[64 + c] + p.bsp[c];
        short hi = f2bf(dv);
        int off = (c >> 5) * 512 + ((row & 15) + (((c & 31) >> 3) << 4)) * 8 + (c & 7);
        XFH(row >> 4)[off] = hi; XFL(row >> 4)[off] = f2bf(dv - bf2f(hi));
    }

    for (int st = 0; st < 12; ++st) {
        // ---- P0: h_in (h0 or dh2 of prev dh1) -> xf kc2..5 hi/lo ----
        if (st == 0) {
            for (int i = t; i < 4096; i += 1024) {
                int m2 = i >> 11, pos = i & 2047;
                int kc = pos >> 9, ll = (pos >> 3) & 63, j = pos & 7;
                int row = m2 * 16 + (ll & 15), kh = kc * 32 + ((ll >> 4) << 3) + j;
                float v = p.h0[(s * 32 + row) * 128 + kh];
                short hi = f2bf(v);
                XFH(m2)[(kc + 2) * 512 + ll * 8 + j] = hi;
                XFL(m2)[(kc + 2) * 512 + ll * 8 + j] = f2bf(v - bf2f(hi));
            }
        } else {
            float4v hacc = {0.f, 0.f, 0.f, 0.f};
            const short* ap = dh1f + mt * 16384 + l * 8;
            const short* bp = p.Wd2f + (size_t)w8 * 16384 + l * 8;
#pragma unroll 1
            for (int kt = 0; kt < 4; ++kt) {
                short8v B[8], A[8];
#pragma unroll
                for (int kk = 0; kk < 8; ++kk)
                    B[kk] = *(const short8v*)(bp + (kt * 8 + kk) * 512);
#pragma unroll
                for (int kk = 0; kk < 8; ++kk)
                    A[kk] = *(const short8v*)(ap + (kt * 8 + kk) * 512);
#pragma unroll
                for (int kk = 0; kk < 8; ++kk)
                    hacc = __builtin_amdgcn_mfma_f32_16x16x32_bf16(A[kk], B[kk], hacc, 0, 0, 0);
            }
            int kx = 64 + colb, kcx = kx >> 5, jx = kx & 7, lxb = ((kx & 31) >> 3) << 4;
            float bb2 = p.bd2[colb];
#pragma unroll
            for (int r = 0; r < 4; ++r) {
                float hn = fmaxf(BN_SF * (hacc[r] + bb2), 0.f);
                short hi = f2bf(hn);
                int off = kcx * 512 + (rbase + r + lxb) * 8 + jx;
                XFH(mt)[off] = hi; XFL(mt)[off] = f2bf(hn - bf2f(hi));
            }
        }
        __syncthreads();  // S1

        // ---- P1: gates (3-term hi/lo MFMA, batched-2) + LSTM pointwise ----
        {
            float4v ga[4] = {{0,0,0,0},{0,0,0,0},{0,0,0,0},{0,0,0,0}};
#pragma unroll 1
            for (int kt = 0; kt < 3; ++kt) {
                short8v BH[2][4], BL[2][4], AH[2], AL[2];
#pragma unroll
                for (int kk = 0; kk < 2; ++kk) {
                    int kc = kt * 2 + kk;
#pragma unroll
                    for (int q = 0; q < 4; ++q) {
                        int nf = w8 + 8 * q;
                        BH[kk][q] = *(const short8v*)(p.WgHi + (size_t)nf * 3072 + kc * 512 + l * 8);
                        BL[kk][q] = *(const short8v*)(p.WgLo + (size_t)nf * 3072 + kc * 512 + l * 8);
                    }
                    AH[kk] = *(const short8v*)(XFH(mt) + kc * 512 + l * 8);
                    AL[kk] = *(const short8v*)(XFL(mt) + kc * 512 + l * 8);
                }
#pragma unroll
                for (int kk = 0; kk < 2; ++kk)
#pragma unroll
                    for (int q = 0; q < 4; ++q) {
                        ga[q] = __builtin_amdgcn_mfma_f32_16x16x32_bf16(AH[kk], BH[kk][q], ga[q], 0, 0, 0);
                        ga[q] = __builtin_amdgcn_mfma_f32_16x16x32_bf16(AH[kk], BL[kk][q], ga[q], 0, 0, 0);
                        ga[q] = __builtin_amdgcn_mfma_f32_16x16x32_bf16(AL[kk], BH[kk][q], ga[q], 0, 0, 0);
                    }
            }
            float bI = p.bih[colb]       + p.bhh[colb];
            float bF = p.bih[colb + 128] + p.bhh[colb + 128];
            float bG = p.bih[colb + 256] + p.bhh[colb + 256];
            float bO = p.bih[colb + 384] + p.bhh[colb + 384];
            int kcm = colb >> 5, jm = colb & 7, lmb = ((colb & 31) >> 3) << 4;
#pragma unroll
            for (int r = 0; r < 4; ++r) {
                int row = mt * 16 + rbase + r;
                float cn = sigm(ga[1][r] + bF) * cr[r] + sigm(ga[0][r] + bI) * tanhf(ga[2][r] + bG);
                cr[r] = cn;
                float hn = sigm(ga[3][r] + bO) * tanhf(cn);
                shF[row][colb] = hn;
                xmf[mt * 2048 + kcm * 512 + (rbase + r + lmb) * 8 + jm] = f2bf(hn);
            }
        }
        __syncthreads();  // S2

        // ---- P2: rel (f32, exact -> out) + m1 MFMA (batched-2) -> M1F ----
        if (t < 512) {
            int row = t >> 4, d = (t >> 3) & 1, seg = t & 7;
            float v = 0.f;
#pragma unroll
            for (int kk = 0; kk < 16; ++kk) {
                int k = seg * 16 + kk;
                v += shF[row][k] * p.Whp[k * 2 + d];
            }
            v += __shfl_xor(v, 1, 64); v += __shfl_xor(v, 2, 64); v += __shfl_xor(v, 4, 64);
            if (seg == 0) {
                v += p.bhp[d];
                srel[row * 2 + d] = v;
                p.out[(size_t)st * 2048 + (s * 32 + row) * 2 + d] = v;
            }
        }
        {
            float4v ma[4] = {{0,0,0,0},{0,0,0,0},{0,0,0,0},{0,0,0,0}};
#pragma unroll 1
            for (int kt = 0; kt < 2; ++kt) {
                short8v A[2], B[2][4];
#pragma unroll
                for (int kk = 0; kk < 2; ++kk) {
                    int kc = kt * 2 + kk;
#pragma unroll
                    for (int q = 0; q < 4; ++q)
                        B[kk][q] = *(const short8v*)(p.Wm1f + (size_t)(w8 * 4 + q) * 2048 + kc * 512 + l * 8);
                    A[kk] = *(const short8v*)(xmf + mt * 2048 + kc * 512 + l * 8);
                }
#pragma unroll
                for (int kk = 0; kk < 2; ++kk)
#pragma unroll
                    for (int q = 0; q < 4; ++q)
                        ma[q] = __builtin_amdgcn_mfma_f32_16x16x32_bf16(A[kk], B[kk][q], ma[q], 0, 0, 0);
            }
#pragma unroll
            for (int q = 0; q < 4; ++q) {
                int col = (w8 * 4 + q) * 16 + (l & 15);
                float uc = p.uv[col], vc = p.uv[512 + col];
                int kcA = col >> 5, jA = col & 7, lA = ((col & 31) >> 3) << 4;
#pragma unroll
                for (int r = 0; r < 4; ++r) {
                    int rowC = mt * 16 + rbase + r;
                    float m1v = fmaxf(BN_SF * (ma[q][r] + sat[rowC] * uc + vc), 0.f);
                    M1F(mt)[kcA * 512 + (rbase + r + lA) * 8 + jA] = f2bf(m1v);
                }
            }
        }
        __syncthreads();  // S3

        // ---- P3: m2 MFMA (batched-2) + per-scene colmax -> sphb ----
        {
            float4v acc2[2][4] = {{{0,0,0,0},{0,0,0,0},{0,0,0,0},{0,0,0,0}},
                                  {{0,0,0,0},{0,0,0,0},{0,0,0,0},{0,0,0,0}}};
            const short* a0p = M1F(0) + l * 8;
            const short* a1p = M1F(1) + l * 8;
            const short* bp = p.Wm2s + (size_t)(w * 4) * 8192 + l * 8;
#pragma unroll 1
            for (int kt = 0; kt < 8; ++kt) {
                short8v A0[2], A1[2], B[2][4];
#pragma unroll
                for (int kk = 0; kk < 2; ++kk) {
                    int kc = kt * 2 + kk;
#pragma unroll
                    for (int q = 0; q < 4; ++q)
                        B[kk][q] = *(const short8v*)(bp + q * 8192 + kc * 512);
                    A0[kk] = *(const short8v*)(a0p + kc * 512);
                    A1[kk] = *(const short8v*)(a1p + kc * 512);
                }
#pragma unroll
                for (int kk = 0; kk < 2; ++kk)
#pragma unroll
                    for (int q = 0; q < 4; ++q) {
                        acc2[0][q] = __builtin_amdgcn_mfma_f32_16x16x32_bf16(A0[kk], B[kk][q], acc2[0][q], 0, 0, 0);
                        acc2[1][q] = __builtin_amdgcn_mfma_f32_16x16x32_bf16(A1[kk], B[kk][q], acc2[1][q], 0, 0, 0);
                    }
            }
#pragma unroll
            for (int q = 0; q < 4; ++q) {
                float m = acc2[0][q][0];
#pragma unroll
                for (int ri = 1; ri < 4; ++ri) m = fmaxf(m, acc2[0][q][ri]);
#pragma unroll
                for (int ri = 0; ri < 4; ++ri) m = fmaxf(m, acc2[1][q][ri]);
                m = fmaxf(m, __shfl_xor(m, 16, 64));
                m = fmaxf(m, __shfl_xor(m, 32, 64));
                if (l < 16) {
                    int col = (w * 4 + q) * 16 + l;
                    sphb[col] = f2bf(fmaxf(BN_SF * (m + p.bm2[col]), 0.f));
                }
            }
        }
        __syncthreads();  // S4

        // ---- P4: di_next -> xf kc0..1 ; phw (batched-2) + dh1h (batched-2) -> dh1f ----
        for (int i = t; i < 2048; i += 1024) {
            int row = i >> 6, c = i & 63;
            float dv = srel[row * 2] * p.Wsp[c] + srel[row * 2 + 1] * p.Wsp[64 + c] + p.bsp[c];
            short hi = f2bf(dv);
            int off = (c >> 5) * 512 + ((row & 15) + (((c & 31) >> 3) << 4)) * 8 + (c & 7);
            XFH(row >> 4)[off] = hi; XFL(row >> 4)[off] = f2bf(dv - bf2f(hi));
        }
        {
            // phw (broadcast-A over Wd1p rows)
            float4v accp[4];
#pragma unroll
            for (int q = 0; q < 4; ++q) {
                int col = (w * 4 + q) * 16 + (l & 15);
                float bb = p.bd1[col];
                accp[q] = (float4v){bb, bb, bb, bb};
            }
#pragma unroll 1
            for (int kt = 0; kt < 16; ++kt) {
                short8v A[2], B[2][4];
#pragma unroll
                for (int kk = 0; kk < 2; ++kk) {
                    int kc = kt * 2 + kk;
#pragma unroll
                    for (int q = 0; q < 4; ++q)
                        B[kk][q] = *(const short8v*)(p.Wd1f + (size_t)(w * 4 + q) * 18432 + (size_t)(4 + kc) * 512 + l * 8);
                    A[kk] = *(const short8v*)(sphb + kc * 32 + ((l >> 4) << 3));
                }
#pragma unroll
                for (int kk = 0; kk < 2; ++kk)
#pragma unroll
                    for (int q = 0; q < 4; ++q)
                        accp[q] = __builtin_amdgcn_mfma_f32_16x16x32_bf16(A[kk], B[kk][q], accp[q], 0, 0, 0);
            }
            // dh1h
            float4v acch[4][2];
#pragma unroll
            for (int q = 0; q < 4; ++q) {
                acch[q][0] = (float4v){0.f, 0.f, 0.f, 0.f};
                acch[q][1] = (float4v){0.f, 0.f, 0.f, 0.f};
            }
#pragma unroll 1
            for (int kt = 0; kt < 2; ++kt) {
                short8v A0[2], A1[2], B[2][4];
#pragma unroll
                for (int kk = 0; kk < 2; ++kk) {
                    int kc = kt * 2 + kk;
#pragma unroll
                    for (int q = 0; q < 4; ++q)
                        B[kk][q] = *(const short8v*)(p.Wd1f + (size_t)(w * 4 + q) * 18432 + (size_t)kc * 512 + l * 8);
                    A0[kk] = *(const short8v*)(xmf + kc * 512 + l * 8);
                    A1[kk] = *(const short8v*)(xmf + 2048 + kc * 512 + l * 8);
                }
#pragma unroll
                for (int kk = 0; kk < 2; ++kk)
#pragma unroll
                    for (int q = 0; q < 4; ++q) {
                        acch[q][0] = __builtin_amdgcn_mfma_f32_16x16x32_bf16(A0[kk], B[kk][q], acch[q][0], 0, 0, 0);
                        acch[q][1] = __builtin_amdgcn_mfma_f32_16x16x32_bf16(A1[kk], B[kk][q], acch[q][1], 0, 0, 0);
                    }
            }
#pragma unroll
            for (int q = 0; q < 4; ++q) {
                int col = (w * 4 + q) * 16 + (l & 15);
                int kcD = col >> 5, jD = col & 7, lD = ((col & 31) >> 3) << 4;
#pragma unroll
                for (int m2i = 0; m2i < 2; ++m2i) {
#pragma unroll
                    for (int r = 0; r < 4; ++r) {
                        float v = fmaxf(BN_SF * (acch[q][m2i][r] + accp[q][r]), 0.f);
                        dh1f[m2i * 16384 + kcD * 512 + (rbase + r + lD) * 8 + jD] = f2bf(v);
                    }
                }
            }
        }
        __syncthreads();  // S5
    }

    // ---- epilogue: final h = relu(BN*(dh1 @ Wd2 + bd2)) -> out ----
    {
        float4v hacc = {0.f, 0.f, 0.f, 0.f};
        const short* ap = dh1f + mt * 16384 + l * 8;
        const short* bp = p.Wd2f + (size_t)w8 * 16384 + l * 8;
#pragma unroll 1
        for (int kt = 0; kt < 4; ++kt) {
            short8v B[8], A[8];
#pragma unroll
            for (int kk = 0; kk < 8; ++kk)
                B[kk] = *(const short8v*)(bp + (kt * 8 + kk) * 512);
#pragma unroll
            for (int kk = 0; kk < 8; ++kk)
                A[kk] = *(const short8v*)(ap + (kt * 8 + kk) * 512);
#pragma unroll
            for (int kk = 0; kk < 8; ++kk)
                hacc = __builtin_amdgcn_mfma_f32_16x16x32_bf16(A[kk], B[kk], hacc, 0, 0, 0);
        }
        float bb2 = p.bd2[colb];
#pragma unroll
        for (int r = 0; r < 4; ++r)
            p.out[24576 + (s * 32 + mt * 16 + rbase + r) * 128 + colb] =
                fmaxf(BN_SF * (hacc[r] + bb2), 0.f);
    }
#undef XFH
#undef XFL
#undef M1F
}

extern "C" void kernel_launch(void* const* d_in, const int* in_sizes, int n_in,
                              void* d_out, int out_size, void* d_ws, size_t ws_size,
                              hipStream_t stream) {
    float* ws = (float*)d_ws;
    float* uv   = ws;                       // 1024 f32
    short* sbase = (short*)(ws + 1024);
    short* Wm2s = sbase;                    // 524288
    short* Wd1f = Wm2s + 524288;            // 1179648
    short* Wd2f = Wd1f + 1179648;           // 131072
    short* Wm1f = Wd2f + 131072;            // 65536
    short* WgHi = Wm1f + 65536;             // 98304
    short* WgLo = WgHi + 98304;             // 98304

    SetupP sp;
    sp.Wm2  = (const float*)d_in[28];
    sp.Wd1  = (const float*)d_in[30];
    sp.Wd2  = (const float*)d_in[32];
    sp.Wm1  = (const float*)d_in[26];
    sp.Wih  = (const float*)d_in[10];
    sp.Whh  = (const float*)d_in[11];
    sp.Wpat = (const float*)d_in[20];
    sp.bpat = (const float*)d_in[21];
    sp.bm1  = (const float*)d_in[27];
    sp.Wm2s = Wm2s; sp.Wd1f = Wd1f; sp.Wd2f = Wd2f;
    sp.Wm1f = Wm1f; sp.WgHi = WgHi; sp.WgLo = WgLo;
    sp.uv = uv;

    MainP mp;
    mp.lpr  = (const float*)d_in[1];
    mp.h0   = (const float*)d_in[2];
    mp.c0   = (const float*)d_in[3];
    mp.at0  = (const float*)d_in[6];
    mp.Wsp  = (const float*)d_in[8];
    mp.bsp  = (const float*)d_in[9];
    mp.bih  = (const float*)d_in[12];
    mp.bhh  = (const float*)d_in[13];
    mp.Whp  = (const float*)d_in[14];
    mp.bhp  = (const float*)d_in[15];
    mp.bm2  = (const float*)d_in[29];
    mp.bd1  = (const float*)d_in[31];
    mp.bd2  = (const float*)d_in[33];
    mp.uv   = uv;
    mp.Wm2s = Wm2s; mp.Wd1f = Wd1f; mp.Wd2f = Wd2f;
    mp.Wm1f = Wm1f; mp.WgHi = WgHi; mp.WgLo = WgLo;
    mp.out  = (float*)d_out;

    k_setup<<<2048, 256, 0, stream>>>(sp);
    k_main<<<32, 1024, 0, stream>>>(mp);
}